// Round 4
// baseline (1214.829 us; speedup 1.0000x reference)
//
#include <hip/hip_runtime.h>
#include <hip/hip_bf16.h>
#include <stdint.h>

typedef unsigned short u16;
typedef unsigned int   u32;
typedef __bf16 bf16_t;
typedef bf16_t bf16x8 __attribute__((ext_vector_type(8)));
typedef float  f32x4  __attribute__((ext_vector_type(4)));

#define NB     4096
#define LSEQ   28
#define DEMB   300
#define KREAL  8400      // 300*28
#define KPAD   8448      // 264*32
#define NPAIRS 8386560   // 4096*4095/2

#define KP1    1504      // conv1/conv2 K: 1500 padded to 47*32
#define KP3    3008      // conv3 K: 3000 padded to 94*32
#define N1TOT  53248     // 4096*13
#define N2TOT  20480     // 4096*5

__device__ __forceinline__ u16 f2bf(float f) {
  u32 u = __float_as_uint(f);
  u32 r = (u + 0x7fffu + ((u >> 16) & 1u)) >> 16;  // RNE
  return (u16)r;
}

// async global->LDS 16B copy; LDS dest = wave-uniform base + lane*16
__device__ __forceinline__ void cp16(const void* g, void* l) {
  __builtin_amdgcn_global_load_lds((const __attribute__((address_space(1))) void*)g,
                                   (__attribute__((address_space(3))) void*)l, 16, 0, 0);
}

// ================== shared MFMA K-loop core ==================
// 128x128 tile, BK=32, 256 threads. Double-buffered LDS (static buffers),
// async cp16 staging with XOR-swizzled chunk columns (bank-conflict-free reads),
// manual vmcnt(4) + raw s_barrier pipeline (prefetch next BK while computing).
// Staging swizzle: LDS slot (row, ch) holds global chunk (row, ch ^ ((row>>1)&3)).
#define MMA_CORE(PA, PB, KpadV, kBegV, kEndV)                                          \
  {                                                                                    \
    int c0 = tid, c1 = tid + 256;                                                      \
    int r0 = c0 >> 2, r1 = c1 >> 2;                                                    \
    int s0 = (c0 & 3) ^ ((r0 >> 1) & 3);                                               \
    int s1 = (c1 & 3) ^ ((r1 >> 1) & 3);                                               \
    const u16* gA0 = (PA) + (size_t)r0 * (KpadV) + s0 * 8;                             \
    const u16* gB0 = (PB) + (size_t)r0 * (KpadV) + s0 * 8;                             \
    const u16* gA1 = (PA) + (size_t)r1 * (KpadV) + s1 * 8;                             \
    const u16* gB1 = (PB) + (size_t)r1 * (KpadV) + s1 * 8;                             \
    int wofs = wave * 512;                                                             \
    int rsel = lane & 15;                                                              \
    int sc   = ((lane >> 4) ^ ((rsel >> 1) & 3)) * 8;                                  \
    int aro  = (wm * 64 + rsel) * 32 + sc;                                             \
    int bro  = (wn * 64 + rsel) * 32 + sc;                                             \
    int nIt  = ((kEndV) - (kBegV)) >> 5;                                               \
    cp16(gA0 + (kBegV), As0 + wofs);        cp16(gB0 + (kBegV), Bs0 + wofs);           \
    cp16(gA1 + (kBegV), As0 + 2048 + wofs); cp16(gB1 + (kBegV), Bs0 + 2048 + wofs);    \
    for (int i = 0; i < nIt; i += 2) {                                                 \
      __builtin_amdgcn_s_barrier();                                                    \
      if (i + 1 < nIt) {                                                               \
        int kk = (kBegV) + ((i + 1) << 5);                                             \
        cp16(gA0 + kk, As1 + wofs);        cp16(gB0 + kk, Bs1 + wofs);                 \
        cp16(gA1 + kk, As1 + 2048 + wofs); cp16(gB1 + kk, Bs1 + 2048 + wofs);          \
        __builtin_amdgcn_s_waitcnt(0x0F74); /* vmcnt(4) */                             \
      } else {                                                                         \
        __builtin_amdgcn_s_waitcnt(0x0F70); /* vmcnt(0) */                             \
      }                                                                                \
      __builtin_amdgcn_s_barrier();                                                    \
      {                                                                                \
        bf16x8 af[4], bfr[4];                                                          \
        _Pragma("unroll")                                                              \
        for (int m = 0; m < 4; ++m) {                                                  \
          af[m]  = *(const bf16x8*)(const void*)(As0 + aro + m * 512);                 \
          bfr[m] = *(const bf16x8*)(const void*)(Bs0 + bro + m * 512);                 \
        }                                                                              \
        _Pragma("unroll")                                                              \
        for (int mi = 0; mi < 4; ++mi)                                                 \
          _Pragma("unroll")                                                            \
          for (int mj = 0; mj < 4; ++mj)                                               \
            acc[mi][mj] = __builtin_amdgcn_mfma_f32_16x16x32_bf16(af[mi], bfr[mj],     \
                                                                  acc[mi][mj], 0, 0, 0);\
      }                                                                                \
      if (i + 1 >= nIt) break;                                                         \
      __builtin_amdgcn_s_barrier();                                                    \
      if (i + 2 < nIt) {                                                               \
        int kk = (kBegV) + ((i + 2) << 5);                                             \
        cp16(gA0 + kk, As0 + wofs);        cp16(gB0 + kk, Bs0 + wofs);                 \
        cp16(gA1 + kk, As0 + 2048 + wofs); cp16(gB1 + kk, Bs0 + 2048 + wofs);          \
        __builtin_amdgcn_s_waitcnt(0x0F74); /* vmcnt(4) */                             \
      } else {                                                                         \
        __builtin_amdgcn_s_waitcnt(0x0F70); /* vmcnt(0) */                             \
      }                                                                                \
      __builtin_amdgcn_s_barrier();                                                    \
      {                                                                                \
        bf16x8 af[4], bfr[4];                                                          \
        _Pragma("unroll")                                                              \
        for (int m = 0; m < 4; ++m) {                                                  \
          af[m]  = *(const bf16x8*)(const void*)(As1 + aro + m * 512);                 \
          bfr[m] = *(const bf16x8*)(const void*)(Bs1 + bro + m * 512);                 \
        }                                                                              \
        _Pragma("unroll")                                                              \
        for (int mi = 0; mi < 4; ++mi)                                                 \
          _Pragma("unroll")                                                            \
          for (int mj = 0; mj < 4; ++mj)                                               \
            acc[mi][mj] = __builtin_amdgcn_mfma_f32_16x16x32_bf16(af[mi], bfr[mj],     \
                                                                  acc[mi][mj], 0, 0, 0);\
      }                                                                                \
    }                                                                                  \
  }

#define MMA_PROLOGUE                                                                   \
  __shared__ alignas(16) u16 As0[4096], Bs0[4096], As1[4096], Bs1[4096];               \
  int tid = threadIdx.x;                                                               \
  int lane = tid & 63, wave = tid >> 6, wm = wave >> 1, wn = wave & 1;                 \
  f32x4 acc[4][4];                                                                     \
  _Pragma("unroll")                                                                    \
  for (int i = 0; i < 4; ++i)                                                          \
    _Pragma("unroll")                                                                  \
    for (int j = 0; j < 4; ++j) acc[i][j] = (f32x4){0.f, 0.f, 0.f, 0.f};

// ---------------- fused pad+convert of all three conv weights ----------------
__global__ void wconv_k(const float* __restrict__ w1, const float* __restrict__ w2,
                        const float* __restrict__ w3, u16* __restrict__ Aw1,
                        u16* __restrict__ Aw2, u16* __restrict__ Aw3) {
  int idx = blockIdx.x * 256 + threadIdx.x;
  const int t1 = 384 * KP1, t2 = 640 * KP1, t3 = 128 * KP3;
  if (idx < t1) {
    int m = idx / KP1, k = idx - m * KP1;
    Aw1[idx] = (m < 300 && k < 1500) ? f2bf(w1[m * 1500 + k]) : (u16)0;
  } else if ((idx -= t1) < t2) {
    int m = idx / KP1, k = idx - m * KP1;
    Aw2[idx] = (m < 600 && k < 1500) ? f2bf(w2[m * 1500 + k]) : (u16)0;
  } else if ((idx -= t2) < t3) {
    int m = idx / KP3, k = idx - m * KP3;
    Aw3[idx] = (m < 100 && k < 3000) ? f2bf(w3[m * 3000 + k]) : (u16)0;
  }
}

// ---------------- embedding row scales: min(1, 1/(||row||+1e-7)) ----------------
__global__ __launch_bounds__(256) void scale_k(const float* __restrict__ emb,
                                               float* __restrict__ scale) {
  int r = blockIdx.x * 4 + (threadIdx.x >> 6);
  int lane = threadIdx.x & 63;
  const float* row = emb + (size_t)r * DEMB;
  float s = 0.f;
  for (int d = lane; d < DEMB; d += 64) { float v = row[d]; s += v * v; }
  for (int off = 32; off; off >>= 1) s += __shfl_xor(s, off, 64);
  if (lane == 0) scale[r] = fminf(1.f, 1.f / (sqrtf(s) + 1e-7f));
}

// ---------------- gather -> Xb bf16 [4096][8448], layout k = d*28 + l ----------------
__global__ __launch_bounds__(256) void embed_k(const int* __restrict__ x,
                                               const float* __restrict__ emb,
                                               const float* __restrict__ scale,
                                               u16* __restrict__ Xb) {
  __shared__ alignas(16) u16 es[KPAD];
  int b = blockIdx.x, tid = threadIdx.x;
  if (tid < KPAD - KREAL) es[KREAL + tid] = 0;
  const int* xr = x + b * LSEQ;
  for (int l = 0; l < LSEQ; ++l) {
    int v = xr[l];
    float s = scale[v];
    const float* er = emb + (size_t)v * DEMB;
    for (int d = tid; d < DEMB; d += 256) es[d * LSEQ + l] = f2bf(er[d] * s);
  }
  __syncthreads();
  uint4* dst = (uint4*)(Xb + (size_t)b * KPAD);
  const uint4* s4 = (const uint4*)es;
  for (int i = tid; i < KPAD / 8; i += 256) dst[i] = s4[i];
}

// ---------------- im2col for conv1: Xb row b -> 13 rows of X1 [.][1504] ----------------
__global__ __launch_bounds__(256) void im2col1_k(const u16* __restrict__ Xb, int b0,
                                                 u16* __restrict__ X1) {
  __shared__ alignas(16) u16 xr[KPAD];
  int b = b0 + blockIdx.x, tid = threadIdx.x;
  const uint4* src = (const uint4*)(Xb + (size_t)b * KPAD);
  uint4* d4 = (uint4*)xr;
  for (int i = tid; i < KPAD / 8; i += 256) d4[i] = src[i];
  __syncthreads();
  for (int task = tid; task < 13 * 188; task += 256) {
    int t = task / 188, c = task - t * 188;
    uint4 v;
    u32 wv[4];
    #pragma unroll
    for (int jj = 0; jj < 4; ++jj) {
      u32 pk = 0;
      #pragma unroll
      for (int h = 0; h < 2; ++h) {
        int idx = c * 8 + jj * 2 + h;
        int ci = idx / 5, k = idx - ci * 5;
        int pos = 2 * t + k - 1;
        u16 e = 0;
        if (idx < 1500 && pos >= 0) e = xr[ci * 28 + pos];
        pk |= ((u32)e) << (16 * h);
      }
      wv[jj] = pk;
    }
    v.x = wv[0]; v.y = wv[1]; v.z = wv[2]; v.w = wv[3];
    *(uint4*)(X1 + ((size_t)(blockIdx.x * 13 + t)) * KP1 + c * 8) = v;
  }
}

// ---------------- BN stats over row-major [C][Ntot]: A=g*inv, B=be-mean*A ----------------
__global__ __launch_bounds__(256) void stats_k(const float* __restrict__ src, int Ntot,
                                               const float* __restrict__ g,
                                               const float* __restrict__ be,
                                               float* __restrict__ bnA, float* __restrict__ bnB) {
  int c = blockIdx.x, tid = threadIdx.x;
  const float* row = src + (size_t)c * Ntot;
  float s = 0.f, sq = 0.f;
  for (int i = tid; i < Ntot; i += 256) { float v = row[i]; s += v; sq += v * v; }
  for (int off = 32; off; off >>= 1) { s += __shfl_xor(s, off, 64); sq += __shfl_xor(sq, off, 64); }
  __shared__ float l1[4], l2[4];
  int wave = tid >> 6, lane = tid & 63;
  if (lane == 0) { l1[wave] = s; l2[wave] = sq; }
  __syncthreads();
  if (tid == 0) {
    float S = l1[0] + l1[1] + l1[2] + l1[3];
    float Q = l2[0] + l2[1] + l2[2] + l2[3];
    float mean = S / Ntot, var = Q / Ntot - mean * mean;
    float inv = rsqrtf(var + 1e-5f);
    float A = g[c] * inv;
    bnA[c] = A; bnB[c] = be[c] - mean * A;
  }
}

// ---------------- im2col for conv2: bn1+relu(C1) -> X2 [4096*5][1504] ----------------
__global__ __launch_bounds__(256) void im2col2_k(const float* __restrict__ C1,
                                                 const float* __restrict__ bnA,
                                                 const float* __restrict__ bnB,
                                                 u16* __restrict__ X2) {
  __shared__ u16 ys[3900];
  int b = blockIdx.x, tid = threadIdx.x;
  for (int i = tid; i < 3900; i += 256) {
    int ci = i / 13, t = i - ci * 13;
    float v = fmaxf(0.f, fmaf(C1[(size_t)ci * N1TOT + b * 13 + t], bnA[ci], bnB[ci]));
    ys[i] = f2bf(v);
  }
  __syncthreads();
  for (int task = tid; task < 5 * 188; task += 256) {
    int t = task / 188, c = task - t * 188;
    uint4 v;
    u32 wv[4];
    #pragma unroll
    for (int jj = 0; jj < 4; ++jj) {
      u32 pk = 0;
      #pragma unroll
      for (int h = 0; h < 2; ++h) {
        int idx = c * 8 + jj * 2 + h;
        int ci = idx / 5, k = idx - ci * 5;
        u16 e = (idx < 1500) ? ys[ci * 13 + 2 * t + k] : (u16)0;
        pk |= ((u32)e) << (16 * h);
      }
      wv[jj] = pk;
    }
    v.x = wv[0]; v.y = wv[1]; v.z = wv[2]; v.w = wv[3];
    *(uint4*)(X2 + ((size_t)b * 5 + t) * KP1 + c * 8) = v;
  }
}

// ---------------- im2col for conv3: bn2+relu(C2) -> X3 [4096][3008] ----------------
__global__ __launch_bounds__(128) void im2col3_k(const float* __restrict__ C2,
                                                 const float* __restrict__ bnA,
                                                 const float* __restrict__ bnB,
                                                 u16* __restrict__ X3) {
  int b = blockIdx.x, tid = threadIdx.x;
  for (int c = tid; c < 376; c += 128) {
    uint4 v;
    u32 wv[4];
    #pragma unroll
    for (int jj = 0; jj < 4; ++jj) {
      u32 pk = 0;
      #pragma unroll
      for (int h = 0; h < 2; ++h) {
        int idx = c * 8 + jj * 2 + h;
        u16 e = 0;
        if (idx < 3000) {
          int ci = idx / 5, k = idx - ci * 5;
          float val = fmaxf(0.f, fmaf(C2[(size_t)ci * N2TOT + b * 5 + k], bnA[ci], bnB[ci]));
          e = f2bf(val);
        }
        pk |= ((u32)e) << (16 * h);
      }
      wv[jj] = pk;
    }
    v.x = wv[0]; v.y = wv[1]; v.z = wv[2]; v.w = wv[3];
    *(uint4*)(X3 + (size_t)b * KP3 + c * 8) = v;
  }
}

// ---------------- GEMM C = A . B^T  (A:[Mpad][Kpad] bf16, B:[ntiles*128][Kpad] bf16) ----------------
__global__ __launch_bounds__(256) void gemm_k(const u16* __restrict__ A,
                                              const u16* __restrict__ B,
                                              int Kpad, int M, int NtotC, int n0,
                                              float* __restrict__ C) {
  MMA_PROLOGUE
  int tn = blockIdx.x, tm = blockIdx.y;
  const u16* PA = A + (size_t)(tm * 128) * Kpad;
  const u16* PB = B + (size_t)(tn * 128) * Kpad;
  MMA_CORE(PA, PB, Kpad, 0, Kpad)

  int rb = wm * 64 + ((lane >> 4) << 2);
  int cb = wn * 64 + (lane & 15);
  #pragma unroll
  for (int mi = 0; mi < 4; ++mi)
    #pragma unroll
    for (int r = 0; r < 4; ++r) {
      int m = tm * 128 + rb + mi * 16 + r;
      if (m < M) {
        float* crow = C + (size_t)m * NtotC + n0 + tn * 128 + cb;
        #pragma unroll
        for (int mj = 0; mj < 4; ++mj) crow[mj * 16] = acc[mi][mj][r];
      }
    }
}

// ---------------- conv3 partial GEMM, split-K=3: Ph[(s*32+tn)][m*128+n] ----------------
__global__ __launch_bounds__(256) void gemm3p_k(const u16* __restrict__ A,
                                                const u16* __restrict__ B,
                                                float* __restrict__ Ph) {
  MMA_PROLOGUE
  int tn = blockIdx.x, s = blockIdx.y;
  int kBeg = (s == 0) ? 0 : 1024 + (s - 1) * 992;
  int kEnd = (s == 0) ? 1024 : kBeg + 992;
  const u16* PA = A;
  const u16* PB = B + (size_t)(tn * 128) * KP3;
  MMA_CORE(PA, PB, KP3, kBeg, kEnd)

  float* po = Ph + ((size_t)(s * 32 + tn)) * 16384;
  int rb = wm * 64 + ((lane >> 4) << 2);
  int cb = wn * 64 + (lane & 15);
  #pragma unroll
  for (int mi = 0; mi < 4; ++mi)
    #pragma unroll
    for (int r = 0; r < 4; ++r) {
      int m = rb + mi * 16 + r;
      #pragma unroll
      for (int mj = 0; mj < 4; ++mj) po[(size_t)m * 128 + cb + mj * 16] = acc[mi][mj][r];
    }
}

// ---------------- finalize conv3: sum partials + bias, tanh, write h, normalize -> Fn ----------------
__global__ __launch_bounds__(64) void fin_k(const float* __restrict__ Ph,
                                            const float* __restrict__ b3,
                                            float* __restrict__ out, u16* __restrict__ Fn) {
  int b = blockIdx.x, lane = threadIdx.x;
  int tn = b >> 7, bl = b & 127;
  const float* base = Ph + (size_t)tn * 16384 + bl;
  float v0 = b3[lane];
  #pragma unroll
  for (int s = 0; s < 3; ++s) v0 += base[(size_t)s * 32 * 16384 + lane * 128];
  v0 = tanhf(v0);
  float v1 = 0.f;
  if (lane + 64 < 100) {
    v1 = b3[lane + 64];
    #pragma unroll
    for (int s = 0; s < 3; ++s) v1 += base[(size_t)s * 32 * 16384 + (lane + 64) * 128];
    v1 = tanhf(v1);
  }
  float s = v0 * v0 + v1 * v1;
  for (int off = 32; off; off >>= 1) s += __shfl_xor(s, off, 64);
  float rn = rsqrtf(s);
  out[(size_t)b * 100 + lane] = v0;
  if (lane + 64 < 100) out[(size_t)b * 100 + lane + 64] = v1;
  u16* orow = Fn + (size_t)b * 128;
  orow[lane]      = f2bf(v0 * rn);
  orow[lane + 64] = (lane + 64 < 100) ? f2bf(v1 * rn) : (u16)0;
}

// ---------------- input gram, split-K=2: full 128x128 partial tiles ----------------
__global__ __launch_bounds__(256) void gram_part_k(const u16* __restrict__ P,
                                                   float* __restrict__ Pout) {
  MMA_PROLOGUE
  int tile = blockIdx.x;
  int q = tile, ti = 0;
  while (q >= 32 - ti) { q -= 32 - ti; ++ti; }
  int tj = ti + q;
  int s = blockIdx.y;
  int kBeg = s * (KPAD / 2), kEnd = kBeg + (KPAD / 2);
  const u16* PA = P + (size_t)ti * 128 * KPAD;
  const u16* PB = P + (size_t)tj * 128 * KPAD;
  MMA_CORE(PA, PB, KPAD, kBeg, kEnd)

  float* po = Pout + ((size_t)(s * 528 + tile)) * 16384;
  int rb = wm * 64 + ((lane >> 4) << 2);
  int cb = wn * 64 + (lane & 15);
  #pragma unroll
  for (int mi = 0; mi < 4; ++mi)
    #pragma unroll
    for (int r = 0; r < 4; ++r) {
      int row = rb + mi * 16 + r;
      #pragma unroll
      for (int mj = 0; mj < 4; ++mj) po[(size_t)row * 128 + cb + mj * 16] = acc[mi][mj][r];
    }
}

// ---------------- reduce split-K partials -> triangular pair list ----------------
__global__ __launch_bounds__(256) void reduce_k(const float* __restrict__ P,
                                                float* __restrict__ outp) {
  int tile = blockIdx.x;
  int q = tile, ti = 0;
  while (q >= 32 - ti) { q -= 32 - ti; ++ti; }
  int tj = ti + q;
  const float4* p0 = (const float4*)(P + (size_t)tile * 16384);
  const float4* p1 = (const float4*)(P + (size_t)(528 + tile) * 16384);
  for (int e = threadIdx.x; e < 4096; e += 256) {
    float4 a = p0[e], bv = p1[e];
    int i = e >> 5;
    int j0 = (e & 31) * 4;
    int gi = ti * 128 + i;
    int gj = tj * 128 + j0;
    float v[4] = {a.x + bv.x, a.y + bv.y, a.z + bv.z, a.w + bv.w};
    #pragma unroll
    for (int u = 0; u < 4; ++u) {
      int gjj = gj + u;
      if (gi < gjj) {
        int pidx = gi * (NB - 1) - ((gi * (gi - 1)) >> 1) + (gjj - gi - 1);
        outp[pidx] = v[u];
      }
    }
  }
}

// ---------------- direct triangular gram (for hidden, K=128) ----------------
__global__ __launch_bounds__(256) void gram_k(const u16* __restrict__ P, int Kpad,
                                              float* __restrict__ outp) {
  MMA_PROLOGUE
  int q = blockIdx.x, ti = 0;
  while (q >= 32 - ti) { q -= 32 - ti; ++ti; }
  int tj = ti + q;
  const u16* PA = P + (size_t)ti * 128 * Kpad;
  const u16* PB = P + (size_t)tj * 128 * Kpad;
  MMA_CORE(PA, PB, Kpad, 0, Kpad)

  int rbase = ti * 128 + wm * 64 + ((lane >> 4) << 2);
  int cbase = tj * 128 + wn * 64 + (lane & 15);
  #pragma unroll
  for (int mi = 0; mi < 4; ++mi)
    #pragma unroll
    for (int mj = 0; mj < 4; ++mj) {
      int gj = cbase + mj * 16;
      #pragma unroll
      for (int r = 0; r < 4; ++r) {
        int gi = rbase + mi * 16 + r;
        if (gi < gj) {
          int p = gi * (NB - 1) - ((gi * (gi - 1)) >> 1) + (gj - gi - 1);
          outp[p] = acc[mi][mj][r];
        }
      }
    }
}

extern "C" void kernel_launch(void* const* d_in, const int* in_sizes, int n_in,
                              void* d_out, int out_size, void* d_ws, size_t ws_size,
                              hipStream_t stream) {
  const int*   x   = (const int*)d_in[0];
  const float* emb = (const float*)d_in[1];
  const float* w1  = (const float*)d_in[2];
  const float* w2  = (const float*)d_in[4];
  const float* w3  = (const float*)d_in[6];
  const float* b3  = (const float*)d_in[7];
  const float* g1  = (const float*)d_in[8];
  const float* be1 = (const float*)d_in[9];
  const float* g2  = (const float*)d_in[10];
  const float* be2 = (const float*)d_in[11];
  float* out = (float*)d_out;

  char* p = (char*)d_ws;
  auto alloc = [&](size_t bytes) { char* r = p; p += (bytes + 255) & ~(size_t)255; return r; };
  float* scale = (float*)alloc((size_t)32000 * 4);
  u16*   Aw1   = (u16*)alloc((size_t)384 * KP1 * 2);
  u16*   Aw2   = (u16*)alloc((size_t)640 * KP1 * 2);
  u16*   Aw3   = (u16*)alloc((size_t)128 * KP3 * 2);
  float* bnA1  = (float*)alloc(300 * 4);
  float* bnB1  = (float*)alloc(300 * 4);
  float* bnA2  = (float*)alloc(600 * 4);
  float* bnB2  = (float*)alloc(600 * 4);
  u16*   Fn    = (u16*)alloc((size_t)NB * 128 * 2);
  // Region A (69.2MB): Xb -> X2 (61.6MB; tail hosts Ph partials for conv3)
  char*  regA  = alloc((size_t)NB * KPAD * 2);
  u16*   Xb    = (u16*)regA;
  u16*   X2    = (u16*)regA;
  float* Ph    = (float*)(regA + 61603840);        // 6.29MB, after X2's 61.60MB
  // Region B (63.9MB): gram partial P half 0 -> C1 -> X3
  char*  regB  = alloc((size_t)300 * N1TOT * 4);
  float* C1    = (float*)regB;
  u16*   X3    = (u16*)regB;
  // Region C (49.2MB): gram partial P overflow -> C2 (also X1 quarter in fallback)
  char*  regC  = alloc((size_t)600 * N2TOT * 4);
  float* C2    = (float*)regC;
  float* Pg    = (float*)regB;                     // 69.2MB spans regB+regC (both dead then)
  // X1: full 160.2MB if ws allows, else quarter (40.0MB) in regC
  size_t used = (size_t)(p - (char*)d_ws);
  size_t x1full_bytes = (size_t)N1TOT * KP1 * 2;   // 160.2MB
  bool   full = (used + x1full_bytes) <= ws_size;
  u16*   X1   = full ? (u16*)alloc(x1full_bytes) : (u16*)regC;

  wconv_k<<<(384 * KP1 + 640 * KP1 + 128 * KP3 + 255) / 256, 256, 0, stream>>>(
      w1, w2, w3, Aw1, Aw2, Aw3);
  scale_k<<<32000 / 4, 256, 0, stream>>>(emb, scale);
  embed_k<<<NB, 256, 0, stream>>>(x, emb, scale, Xb);

  // input_pws: split-K=2 gram (1056 blocks) + reduction
  gram_part_k<<<dim3(528, 2), 256, 0, stream>>>(Xb, Pg);
  reduce_k<<<528, 256, 0, stream>>>(Pg, out + 409600);

  // conv1 (Pg dead; C1 -> regB)
  if (full) {
    im2col1_k<<<NB, 256, 0, stream>>>(Xb, 0, X1);
    gemm_k<<<dim3(416, 3), 256, 0, stream>>>(Aw1, X1, KP1, 300, N1TOT, 0, C1);
  } else {
    for (int q = 0; q < 4; ++q) {
      im2col1_k<<<1024, 256, 0, stream>>>(Xb, q * 1024, X1);
      gemm_k<<<dim3(104, 3), 256, 0, stream>>>(Aw1, X1, KP1, 300, N1TOT, q * 13312, C1);
    }
  }
  stats_k<<<300, 256, 0, stream>>>(C1, N1TOT, g1, be1, bnA1, bnB1);
  im2col2_k<<<NB, 256, 0, stream>>>(C1, bnA1, bnB1, X2);                // X2 overwrites Xb (dead)
  gemm_k<<<dim3(160, 5), 256, 0, stream>>>(Aw2, X2, KP1, 600, N2TOT, 0, C2);
  stats_k<<<600, 256, 0, stream>>>(C2, N2TOT, g2, be2, bnA2, bnB2);
  im2col3_k<<<NB, 128, 0, stream>>>(C2, bnA2, bnB2, X3);                // X3 overwrites C1 (dead)
  gemm3p_k<<<dim3(32, 3), 256, 0, stream>>>(Aw3, X3, Ph);               // conv3 split-K=3 partials
  fin_k<<<NB, 64, 0, stream>>>(Ph, b3, out, Fn);                        // h + normalized Fn
  gram_k<<<528, 256, 0, stream>>>(Fn, 128, out + 409600 + NPAIRS);      // hidden_pws
}

// Round 6
// 1079.227 us; speedup vs baseline: 1.1256x; 1.1256x over previous
//
#include <hip/hip_runtime.h>
#include <hip/hip_bf16.h>
#include <stdint.h>

typedef unsigned short u16;
typedef unsigned int   u32;
typedef __bf16 bf16_t;
typedef bf16_t bf16x8 __attribute__((ext_vector_type(8)));
typedef float  f32x4  __attribute__((ext_vector_type(4)));

#define NB     4096
#define LSEQ   28
#define DEMB   300
#define KREAL  8400      // 300*28
#define KPAD   8448      // 264*32
#define NPAIRS 8386560   // 4096*4095/2

#define KP1    1504      // conv1/conv2 K: 1500 padded to 47*32
#define KP3    3008      // conv3 K: 3000 padded to 94*32
#define N1TOT  53248     // 4096*13
#define N2TOT  20480     // 4096*5

#define GSPLIT 3         // gram split-K parts (KPAD/3 = 2816 = 88*32)

__device__ __forceinline__ u16 f2bf(float f) {
  u32 u = __float_as_uint(f);
  u32 r = (u + 0x7fffu + ((u >> 16) & 1u)) >> 16;  // RNE
  return (u16)r;
}

// async global->LDS 16B copy; LDS dest = wave-uniform base + lane*16
__device__ __forceinline__ void cp16(const void* g, void* l) {
  __builtin_amdgcn_global_load_lds((const __attribute__((address_space(1))) void*)g,
                                   (__attribute__((address_space(3))) void*)l, 16, 0, 0);
}

// ================== shared MFMA K-loop core ==================
// 128x128 tile, BK=32, 256 threads. SINGLE-buffer LDS + __syncthreads (m97
// structure — R4 showed explicit dbuf/vmcnt pipeline regresses: LDS/SGPR
// pressure outweighs prefetch). XOR-swizzled chunk columns at staging keep
// fragment ds_read_b128 bank-conflict-free (R4: SQ_LDS_BANK_CONFLICT -> 0).
// Staging swizzle: LDS slot (row, ch) holds global chunk (row, ch ^ ((row>>1)&3)).
#define MMA_CORE(PA, PB, KpadV, kBegV, kEndV)                                          \
  {                                                                                    \
    int c0 = tid, c1 = tid + 256;                                                      \
    int r0 = c0 >> 2, r1 = c1 >> 2;                                                    \
    int s0 = (c0 & 3) ^ ((r0 >> 1) & 3);                                               \
    int s1 = (c1 & 3) ^ ((r1 >> 1) & 3);                                               \
    const u16* gA0 = (PA) + (size_t)r0 * (KpadV) + s0 * 8;                             \
    const u16* gB0 = (PB) + (size_t)r0 * (KpadV) + s0 * 8;                             \
    const u16* gA1 = (PA) + (size_t)r1 * (KpadV) + s1 * 8;                             \
    const u16* gB1 = (PB) + (size_t)r1 * (KpadV) + s1 * 8;                             \
    int wofs = wave * 512;                                                             \
    int rsel = lane & 15;                                                              \
    int sc   = ((lane >> 4) ^ ((rsel >> 1) & 3)) * 8;                                  \
    int aro  = (wm * 64 + rsel) * 32 + sc;                                             \
    int bro  = (wn * 64 + rsel) * 32 + sc;                                             \
    for (int kk = (kBegV); kk < (kEndV); kk += 32) {                                   \
      cp16(gA0 + kk, As0 + wofs);        cp16(gB0 + kk, Bs0 + wofs);                   \
      cp16(gA1 + kk, As0 + 2048 + wofs); cp16(gB1 + kk, Bs0 + 2048 + wofs);            \
      __syncthreads();                                                                 \
      bf16x8 af[4], bfr[4];                                                            \
      _Pragma("unroll")                                                                \
      for (int m = 0; m < 4; ++m) {                                                    \
        af[m]  = *(const bf16x8*)(const void*)(As0 + aro + m * 512);                   \
        bfr[m] = *(const bf16x8*)(const void*)(Bs0 + bro + m * 512);                   \
      }                                                                                \
      _Pragma("unroll")                                                                \
      for (int mi = 0; mi < 4; ++mi)                                                   \
        _Pragma("unroll")                                                              \
        for (int mj = 0; mj < 4; ++mj)                                                 \
          acc[mi][mj] = __builtin_amdgcn_mfma_f32_16x16x32_bf16(af[mi], bfr[mj],       \
                                                                acc[mi][mj], 0, 0, 0); \
      __syncthreads();                                                                 \
    }                                                                                  \
  }

#define MMA_PROLOGUE                                                                   \
  __shared__ alignas(16) u16 As0[4096], Bs0[4096];                                     \
  int tid = threadIdx.x;                                                               \
  int lane = tid & 63, wave = tid >> 6, wm = wave >> 1, wn = wave & 1;                 \
  f32x4 acc[4][4];                                                                     \
  _Pragma("unroll")                                                                    \
  for (int i = 0; i < 4; ++i)                                                          \
    _Pragma("unroll")                                                                  \
    for (int j = 0; j < 4; ++j) acc[i][j] = (f32x4){0.f, 0.f, 0.f, 0.f};

// ---------------- fused pad+convert of all three conv weights ----------------
__global__ void wconv_k(const float* __restrict__ w1, const float* __restrict__ w2,
                        const float* __restrict__ w3, u16* __restrict__ Aw1,
                        u16* __restrict__ Aw2, u16* __restrict__ Aw3) {
  int idx = blockIdx.x * 256 + threadIdx.x;
  const int t1 = 384 * KP1, t2 = 640 * KP1, t3 = 128 * KP3;
  if (idx < t1) {
    int m = idx / KP1, k = idx - m * KP1;
    Aw1[idx] = (m < 300 && k < 1500) ? f2bf(w1[m * 1500 + k]) : (u16)0;
  } else if ((idx -= t1) < t2) {
    int m = idx / KP1, k = idx - m * KP1;
    Aw2[idx] = (m < 600 && k < 1500) ? f2bf(w2[m * 1500 + k]) : (u16)0;
  } else if ((idx -= t2) < t3) {
    int m = idx / KP3, k = idx - m * KP3;
    Aw3[idx] = (m < 100 && k < 3000) ? f2bf(w3[m * 3000 + k]) : (u16)0;
  }
}

// ---------------- embedding row scales: min(1, 1/(||row||+1e-7)) ----------------
__global__ __launch_bounds__(256) void scale_k(const float* __restrict__ emb,
                                               float* __restrict__ scale) {
  int r = blockIdx.x * 4 + (threadIdx.x >> 6);
  int lane = threadIdx.x & 63;
  const float* row = emb + (size_t)r * DEMB;
  float s = 0.f;
  for (int d = lane; d < DEMB; d += 64) { float v = row[d]; s += v * v; }
  for (int off = 32; off; off >>= 1) s += __shfl_xor(s, off, 64);
  if (lane == 0) scale[r] = fminf(1.f, 1.f / (sqrtf(s) + 1e-7f));
}

// ---------------- gather -> Xb bf16 [4096][8448], layout k = d*28 + l ----------------
__global__ __launch_bounds__(256) void embed_k(const int* __restrict__ x,
                                               const float* __restrict__ emb,
                                               const float* __restrict__ scale,
                                               u16* __restrict__ Xb) {
  __shared__ alignas(16) u16 es[KPAD];
  int b = blockIdx.x, tid = threadIdx.x;
  if (tid < KPAD - KREAL) es[KREAL + tid] = 0;
  const int* xr = x + b * LSEQ;
  for (int l = 0; l < LSEQ; ++l) {
    int v = xr[l];
    float s = scale[v];
    const float* er = emb + (size_t)v * DEMB;
    for (int d = tid; d < DEMB; d += 256) es[d * LSEQ + l] = f2bf(er[d] * s);
  }
  __syncthreads();
  uint4* dst = (uint4*)(Xb + (size_t)b * KPAD);
  const uint4* s4 = (const uint4*)es;
  for (int i = tid; i < KPAD / 8; i += 256) dst[i] = s4[i];
}

// ---------------- im2col for conv1: Xb row b -> 13 rows of X1 [.][1504] ----------------
__global__ __launch_bounds__(256) void im2col1_k(const u16* __restrict__ Xb, int b0,
                                                 u16* __restrict__ X1) {
  __shared__ alignas(16) u16 xr[KPAD];
  int b = b0 + blockIdx.x, tid = threadIdx.x;
  const uint4* src = (const uint4*)(Xb + (size_t)b * KPAD);
  uint4* d4 = (uint4*)xr;
  for (int i = tid; i < KPAD / 8; i += 256) d4[i] = src[i];
  __syncthreads();
  for (int task = tid; task < 13 * 188; task += 256) {
    int t = task / 188, c = task - t * 188;
    uint4 v;
    u32 wv[4];
    #pragma unroll
    for (int jj = 0; jj < 4; ++jj) {
      u32 pk = 0;
      #pragma unroll
      for (int h = 0; h < 2; ++h) {
        int idx = c * 8 + jj * 2 + h;
        int ci = idx / 5, k = idx - ci * 5;
        int pos = 2 * t + k - 1;
        u16 e = 0;
        if (idx < 1500 && pos >= 0) e = xr[ci * 28 + pos];
        pk |= ((u32)e) << (16 * h);
      }
      wv[jj] = pk;
    }
    v.x = wv[0]; v.y = wv[1]; v.z = wv[2]; v.w = wv[3];
    *(uint4*)(X1 + ((size_t)(blockIdx.x * 13 + t)) * KP1 + c * 8) = v;
  }
}

// ---------------- BN stats over row-major [C][Ntot]: A=g*inv, B=be-mean*A ----------------
__global__ __launch_bounds__(256) void stats_k(const float* __restrict__ src, int Ntot,
                                               const float* __restrict__ g,
                                               const float* __restrict__ be,
                                               float* __restrict__ bnA, float* __restrict__ bnB) {
  int c = blockIdx.x, tid = threadIdx.x;
  const float* row = src + (size_t)c * Ntot;
  float s = 0.f, sq = 0.f;
  for (int i = tid; i < Ntot; i += 256) { float v = row[i]; s += v; sq += v * v; }
  for (int off = 32; off; off >>= 1) { s += __shfl_xor(s, off, 64); sq += __shfl_xor(sq, off, 64); }
  __shared__ float l1[4], l2[4];
  int wave = tid >> 6, lane = tid & 63;
  if (lane == 0) { l1[wave] = s; l2[wave] = sq; }
  __syncthreads();
  if (tid == 0) {
    float S = l1[0] + l1[1] + l1[2] + l1[3];
    float Q = l2[0] + l2[1] + l2[2] + l2[3];
    float mean = S / Ntot, var = Q / Ntot - mean * mean;
    float inv = rsqrtf(var + 1e-5f);
    float A = g[c] * inv;
    bnA[c] = A; bnB[c] = be[c] - mean * A;
  }
}

// ---------------- im2col for conv2: bn1+relu(C1) -> X2 [4096*5][1504] ----------------
__global__ __launch_bounds__(256) void im2col2_k(const float* __restrict__ C1,
                                                 const float* __restrict__ bnA,
                                                 const float* __restrict__ bnB,
                                                 u16* __restrict__ X2) {
  __shared__ u16 ys[3900];
  int b = blockIdx.x, tid = threadIdx.x;
  for (int i = tid; i < 3900; i += 256) {
    int ci = i / 13, t = i - ci * 13;
    float v = fmaxf(0.f, fmaf(C1[(size_t)ci * N1TOT + b * 13 + t], bnA[ci], bnB[ci]));
    ys[i] = f2bf(v);
  }
  __syncthreads();
  for (int task = tid; task < 5 * 188; task += 256) {
    int t = task / 188, c = task - t * 188;
    uint4 v;
    u32 wv[4];
    #pragma unroll
    for (int jj = 0; jj < 4; ++jj) {
      u32 pk = 0;
      #pragma unroll
      for (int h = 0; h < 2; ++h) {
        int idx = c * 8 + jj * 2 + h;
        int ci = idx / 5, k = idx - ci * 5;
        u16 e = (idx < 1500) ? ys[ci * 13 + 2 * t + k] : (u16)0;
        pk |= ((u32)e) << (16 * h);
      }
      wv[jj] = pk;
    }
    v.x = wv[0]; v.y = wv[1]; v.z = wv[2]; v.w = wv[3];
    *(uint4*)(X2 + ((size_t)b * 5 + t) * KP1 + c * 8) = v;
  }
}

// ---------------- im2col for conv3: bn2+relu(C2) -> X3 [4096][3008] ----------------
__global__ __launch_bounds__(128) void im2col3_k(const float* __restrict__ C2,
                                                 const float* __restrict__ bnA,
                                                 const float* __restrict__ bnB,
                                                 u16* __restrict__ X3) {
  int b = blockIdx.x, tid = threadIdx.x;
  for (int c = tid; c < 376; c += 128) {
    uint4 v;
    u32 wv[4];
    #pragma unroll
    for (int jj = 0; jj < 4; ++jj) {
      u32 pk = 0;
      #pragma unroll
      for (int h = 0; h < 2; ++h) {
        int idx = c * 8 + jj * 2 + h;
        u16 e = 0;
        if (idx < 3000) {
          int ci = idx / 5, k = idx - ci * 5;
          float val = fmaxf(0.f, fmaf(C2[(size_t)ci * N2TOT + b * 5 + k], bnA[ci], bnB[ci]));
          e = f2bf(val);
        }
        pk |= ((u32)e) << (16 * h);
      }
      wv[jj] = pk;
    }
    v.x = wv[0]; v.y = wv[1]; v.z = wv[2]; v.w = wv[3];
    *(uint4*)(X3 + (size_t)b * KP3 + c * 8) = v;
  }
}

// ---------------- GEMM C = A . B^T  (A:[Mpad][Kpad] bf16, B:[ntiles*128][Kpad] bf16) ----------------
__global__ __launch_bounds__(256) void gemm_k(const u16* __restrict__ A,
                                              const u16* __restrict__ B,
                                              int Kpad, int M, int NtotC, int n0,
                                              float* __restrict__ C) {
  MMA_PROLOGUE
  int tn = blockIdx.x, tm = blockIdx.y;
  const u16* PA = A + (size_t)(tm * 128) * Kpad;
  const u16* PB = B + (size_t)(tn * 128) * Kpad;
  MMA_CORE(PA, PB, Kpad, 0, Kpad)

  int rb = wm * 64 + ((lane >> 4) << 2);
  int cb = wn * 64 + (lane & 15);
  #pragma unroll
  for (int mi = 0; mi < 4; ++mi)
    #pragma unroll
    for (int r = 0; r < 4; ++r) {
      int m = tm * 128 + rb + mi * 16 + r;
      if (m < M) {
        float* crow = C + (size_t)m * NtotC + n0 + tn * 128 + cb;
        #pragma unroll
        for (int mj = 0; mj < 4; ++mj) crow[mj * 16] = acc[mi][mj][r];
      }
    }
}

// ---------------- conv3 partial GEMM, split-K=3: Ph[(s*32+tn)][m*128+n] ----------------
__global__ __launch_bounds__(256) void gemm3p_k(const u16* __restrict__ A,
                                                const u16* __restrict__ B,
                                                float* __restrict__ Ph) {
  MMA_PROLOGUE
  int tn = blockIdx.x, s = blockIdx.y;
  int kBeg = (s == 0) ? 0 : 1024 + (s - 1) * 992;
  int kEnd = (s == 0) ? 1024 : kBeg + 992;
  const u16* PA = A;
  const u16* PB = B + (size_t)(tn * 128) * KP3;
  MMA_CORE(PA, PB, KP3, kBeg, kEnd)

  float* po = Ph + ((size_t)(s * 32 + tn)) * 16384;
  int rb = wm * 64 + ((lane >> 4) << 2);
  int cb = wn * 64 + (lane & 15);
  #pragma unroll
  for (int mi = 0; mi < 4; ++mi)
    #pragma unroll
    for (int r = 0; r < 4; ++r) {
      int m = rb + mi * 16 + r;
      #pragma unroll
      for (int mj = 0; mj < 4; ++mj) po[(size_t)m * 128 + cb + mj * 16] = acc[mi][mj][r];
    }
}

// ---------------- finalize conv3: sum partials + bias, tanh, write h, normalize -> Fn ----------------
__global__ __launch_bounds__(64) void fin_k(const float* __restrict__ Ph,
                                            const float* __restrict__ b3,
                                            float* __restrict__ out, u16* __restrict__ Fn) {
  int b = blockIdx.x, lane = threadIdx.x;
  int tn = b >> 7, bl = b & 127;
  const float* base = Ph + (size_t)tn * 16384 + bl;
  float v0 = b3[lane];
  #pragma unroll
  for (int s = 0; s < 3; ++s) v0 += base[(size_t)s * 32 * 16384 + lane * 128];
  v0 = tanhf(v0);
  float v1 = 0.f;
  if (lane + 64 < 100) {
    v1 = b3[lane + 64];
    #pragma unroll
    for (int s = 0; s < 3; ++s) v1 += base[(size_t)s * 32 * 16384 + (lane + 64) * 128];
    v1 = tanhf(v1);
  }
  float s = v0 * v0 + v1 * v1;
  for (int off = 32; off; off >>= 1) s += __shfl_xor(s, off, 64);
  float rn = rsqrtf(s);
  out[(size_t)b * 100 + lane] = v0;
  if (lane + 64 < 100) out[(size_t)b * 100 + lane + 64] = v1;
  u16* orow = Fn + (size_t)b * 128;
  orow[lane]      = f2bf(v0 * rn);
  orow[lane + 64] = (lane + 64 < 100) ? f2bf(v1 * rn) : (u16)0;
}

// ---------------- input gram, split-K=GSPLIT: full 128x128 partial tiles ----------------
__global__ __launch_bounds__(256) void gram_part_k(const u16* __restrict__ P,
                                                   float* __restrict__ Pout) {
  MMA_PROLOGUE
  int tile = blockIdx.x;
  int q = tile, ti = 0;
  while (q >= 32 - ti) { q -= 32 - ti; ++ti; }
  int tj = ti + q;
  int s = blockIdx.y;
  int kBeg = s * (KPAD / GSPLIT), kEnd = kBeg + (KPAD / GSPLIT);
  const u16* PA = P + (size_t)ti * 128 * KPAD;
  const u16* PB = P + (size_t)tj * 128 * KPAD;
  MMA_CORE(PA, PB, KPAD, kBeg, kEnd)

  float* po = Pout + ((size_t)(s * 528 + tile)) * 16384;
  int rb = wm * 64 + ((lane >> 4) << 2);
  int cb = wn * 64 + (lane & 15);
  #pragma unroll
  for (int mi = 0; mi < 4; ++mi)
    #pragma unroll
    for (int r = 0; r < 4; ++r) {
      int row = rb + mi * 16 + r;
      #pragma unroll
      for (int mj = 0; mj < 4; ++mj) po[(size_t)row * 128 + cb + mj * 16] = acc[mi][mj][r];
    }
}

// ---------------- reduce split-K partials -> triangular pair list ----------------
__global__ __launch_bounds__(256) void reduce_k(const float* __restrict__ P,
                                                float* __restrict__ outp) {
  int tile = blockIdx.x;
  int q = tile, ti = 0;
  while (q >= 32 - ti) { q -= 32 - ti; ++ti; }
  int tj = ti + q;
  const float4* p0 = (const float4*)(P + (size_t)tile * 16384);
  const float4* p1 = (const float4*)(P + (size_t)(528 + tile) * 16384);
  const float4* p2 = (const float4*)(P + (size_t)(1056 + tile) * 16384);
  for (int e = threadIdx.x; e < 4096; e += 256) {
    float4 a = p0[e], bv = p1[e], cv = p2[e];
    int i = e >> 5;
    int j0 = (e & 31) * 4;
    int gi = ti * 128 + i;
    int gj = tj * 128 + j0;
    float v[4] = {a.x + bv.x + cv.x, a.y + bv.y + cv.y,
                  a.z + bv.z + cv.z, a.w + bv.w + cv.w};
    #pragma unroll
    for (int u = 0; u < 4; ++u) {
      int gjj = gj + u;
      if (gi < gjj) {
        int pidx = gi * (NB - 1) - ((gi * (gi - 1)) >> 1) + (gjj - gi - 1);
        outp[pidx] = v[u];
      }
    }
  }
}

// ---------------- direct triangular gram (for hidden, K=128) ----------------
__global__ __launch_bounds__(256) void gram_k(const u16* __restrict__ P, int Kpad,
                                              float* __restrict__ outp) {
  MMA_PROLOGUE
  int q = blockIdx.x, ti = 0;
  while (q >= 32 - ti) { q -= 32 - ti; ++ti; }
  int tj = ti + q;
  const u16* PA = P + (size_t)ti * 128 * Kpad;
  const u16* PB = P + (size_t)tj * 128 * Kpad;
  MMA_CORE(PA, PB, Kpad, 0, Kpad)

  int rbase = ti * 128 + wm * 64 + ((lane >> 4) << 2);
  int cbase = tj * 128 + wn * 64 + (lane & 15);
  #pragma unroll
  for (int mi = 0; mi < 4; ++mi)
    #pragma unroll
    for (int mj = 0; mj < 4; ++mj) {
      int gj = cbase + mj * 16;
      #pragma unroll
      for (int r = 0; r < 4; ++r) {
        int gi = rbase + mi * 16 + r;
        if (gi < gj) {
          int p = gi * (NB - 1) - ((gi * (gi - 1)) >> 1) + (gj - gi - 1);
          outp[p] = acc[mi][mj][r];
        }
      }
    }
}

extern "C" void kernel_launch(void* const* d_in, const int* in_sizes, int n_in,
                              void* d_out, int out_size, void* d_ws, size_t ws_size,
                              hipStream_t stream) {
  const int*   x   = (const int*)d_in[0];
  const float* emb = (const float*)d_in[1];
  const float* w1  = (const float*)d_in[2];
  const float* w2  = (const float*)d_in[4];
  const float* w3  = (const float*)d_in[6];
  const float* b3  = (const float*)d_in[7];
  const float* g1  = (const float*)d_in[8];
  const float* be1 = (const float*)d_in[9];
  const float* g2  = (const float*)d_in[10];
  const float* be2 = (const float*)d_in[11];
  float* out = (float*)d_out;

  char* p = (char*)d_ws;
  auto alloc = [&](size_t bytes) { char* r = p; p += (bytes + 255) & ~(size_t)255; return r; };
  float* scale = (float*)alloc((size_t)32000 * 4);
  u16*   Aw1   = (u16*)alloc((size_t)384 * KP1 * 2);
  u16*   Aw2   = (u16*)alloc((size_t)640 * KP1 * 2);
  u16*   Aw3   = (u16*)alloc((size_t)128 * KP3 * 2);
  float* bnA1  = (float*)alloc(300 * 4);
  float* bnB1  = (float*)alloc(300 * 4);
  float* bnA2  = (float*)alloc(600 * 4);
  float* bnB2  = (float*)alloc(600 * 4);
  u16*   Fn    = (u16*)alloc((size_t)NB * 128 * 2);
  // Region A (69.2MB): Xb -> X2 (61.6MB; tail hosts Ph partials for conv3)
  char*  regA  = alloc((size_t)NB * KPAD * 2);
  u16*   Xb    = (u16*)regA;
  u16*   X2    = (u16*)regA;
  float* Ph    = (float*)(regA + 61603840);        // 6.29MB, after X2's 61.60MB
  // Region B (63.9MB): gram partials (with C) -> C1 -> X3
  char*  regB  = alloc((size_t)300 * N1TOT * 4);
  float* C1    = (float*)regB;
  u16*   X3    = (u16*)regB;
  // Region C (49.2MB): gram partial overflow -> C2 (also X1 quarter in fallback)
  char*  regC  = alloc((size_t)600 * N2TOT * 4);
  float* C2    = (float*)regC;
  float* Pg    = (float*)regB;   // GSPLIT*528*64KB = 103.8MB spans regB+regC (both dead then)
  // X1: full 160.2MB if ws allows, else quarter (40.0MB) in regC
  size_t used = (size_t)(p - (char*)d_ws);
  size_t x1full_bytes = (size_t)N1TOT * KP1 * 2;   // 160.2MB
  bool   full = (used + x1full_bytes) <= ws_size;
  u16*   X1   = full ? (u16*)alloc(x1full_bytes) : (u16*)regC;

  wconv_k<<<(384 * KP1 + 640 * KP1 + 128 * KP3 + 255) / 256, 256, 0, stream>>>(
      w1, w2, w3, Aw1, Aw2, Aw3);
  scale_k<<<32000 / 4, 256, 0, stream>>>(emb, scale);
  embed_k<<<NB, 256, 0, stream>>>(x, emb, scale, Xb);

  // input_pws: split-K=GSPLIT gram (1584 blocks) + reduction
  gram_part_k<<<dim3(528, GSPLIT), 256, 0, stream>>>(Xb, Pg);
  reduce_k<<<528, 256, 0, stream>>>(Pg, out + 409600);

  // conv1 (Pg dead; C1 -> regB)
  if (full) {
    im2col1_k<<<NB, 256, 0, stream>>>(Xb, 0, X1);
    gemm_k<<<dim3(416, 3), 256, 0, stream>>>(Aw1, X1, KP1, 300, N1TOT, 0, C1);
  } else {
    for (int q = 0; q < 4; ++q) {
      im2col1_k<<<1024, 256, 0, stream>>>(Xb, q * 1024, X1);
      gemm_k<<<dim3(104, 3), 256, 0, stream>>>(Aw1, X1, KP1, 300, N1TOT, q * 13312, C1);
    }
  }
  stats_k<<<300, 256, 0, stream>>>(C1, N1TOT, g1, be1, bnA1, bnB1);
  im2col2_k<<<NB, 256, 0, stream>>>(C1, bnA1, bnB1, X2);                // X2 overwrites Xb (dead)
  gemm_k<<<dim3(160, 5), 256, 0, stream>>>(Aw2, X2, KP1, 600, N2TOT, 0, C2);
  stats_k<<<600, 256, 0, stream>>>(C2, N2TOT, g2, be2, bnA2, bnB2);
  im2col3_k<<<NB, 128, 0, stream>>>(C2, bnA2, bnB2, X3);                // X3 overwrites C1 (dead)
  gemm3p_k<<<dim3(32, 3), 256, 0, stream>>>(Aw3, X3, Ph);               // conv3 split-K=3 partials
  fin_k<<<NB, 64, 0, stream>>>(Ph, b3, out, Fn);                        // h + normalized Fn
  gram_k<<<528, 256, 0, stream>>>(Fn, 128, out + 409600 + NPAIRS);      // hidden_pws
}